// Round 9
// baseline (282.653 us; speedup 1.0000x reference)
//
#include <hip/hip_runtime.h>
#include <hip/hip_bf16.h>

#define NB 128
#define LL 512
#define DD 512

typedef __attribute__((ext_vector_type(4))) float  f32x4;
typedef __attribute__((ext_vector_type(8))) short  s16x8;

__device__ __forceinline__ short f2bf(float f) {
    __hip_bfloat16 h = __float2bfloat16(f);
    return *reinterpret_cast<short*>(&h);
}

// monotone float<->uint mapping so atomicMax(uint) == float max
__device__ __forceinline__ unsigned fmap(float f) {
    unsigned u = __float_as_uint(f);
    return (u & 0x80000000u) ? ~u : (u | 0x80000000u);
}
__device__ __forceinline__ float funmap(unsigned u) {
    unsigned b = (u & 0x80000000u) ? (u ^ 0x80000000u) : ~u;
    return __uint_as_float(b);
}

__global__ __launch_bounds__(256) void init_kernel(unsigned* __restrict__ p, int n) {
    int i = blockIdx.x * 256 + threadIdx.x;
    if (i < n) p[i] = 0u;  // 0 < fmap of any real value
}

// Fully sync-free fused kernel: no LDS, no barriers.
// Each wave owns a 64x64 output tile; fragments are loaded DIRECTLY from
// global fp32 (per-batch panels are L2/L3-resident), converted to bf16 in
// registers, MFMA'd. Sum-of-squares is accumulated from the same registers;
// since a wave sees ALL K for its own rows and cols, inv-norms are
// wave-private (shuffles only). Latency hides via occupancy + the compiler
// hoisting loads inside the fully unrolled K-loop (reg budget 512/3).
__global__ __launch_bounds__(256, 3) void simdirect(
        const float* __restrict__ x1, const float* __restrict__ x2,
        const int* __restrict__ mask1, const int* __restrict__ mask2,
        unsigned* __restrict__ rowmax_u, unsigned* __restrict__ colmax_u) {
    int bid = blockIdx.x;
    int lid = (bid & 7) * 256 + (bid >> 3);   // XCD-chunked bijective swizzle (nwg=2048)
    int b   = lid >> 4;
    int tr  = (lid >> 2) & 3;
    int tc  = lid & 3;

    int tid  = threadIdx.x;
    int lane = tid & 63;
    int w    = tid >> 6;
    int wr = w >> 1, wc = w & 1;
    int l15 = lane & 15, lhi = lane >> 4;

    // this wave's row/col panels
    const float* Ab = x1 + ((size_t)b * LL + tr * 128 + wr * 64) * DD;
    const float* Bb = x2 + ((size_t)b * LL + tc * 128 + wc * 64) * DD;

    float ssa[4] = {0.f, 0.f, 0.f, 0.f};   // per-lane partial SS of row fr*16+l15, k-slice lhi
    float ssb[4] = {0.f, 0.f, 0.f, 0.f};   // per-lane partial SS of col fc*16+l15, k-slice lhi

    f32x4 acc[4][4];
    #pragma unroll
    for (int fr = 0; fr < 4; ++fr)
        #pragma unroll
        for (int fc = 0; fc < 4; ++fc) {
            acc[fr][fc].x = 0.f; acc[fr][fc].y = 0.f;
            acc[fr][fc].z = 0.f; acc[fr][fc].w = 0.f;
        }

    #pragma unroll
    for (int ks = 0; ks < 16; ++ks) {
        int kof = ks * 32 + lhi * 8;          // this lane's 8-elem k-slice
        s16x8 af[4], bf[4];
        #pragma unroll
        for (int fr = 0; fr < 4; ++fr) {
            const float* g = Ab + (size_t)(fr * 16 + l15) * DD + kof;
            f32x4 v0 = *reinterpret_cast<const f32x4*>(g);
            f32x4 v1 = *reinterpret_cast<const f32x4*>(g + 4);
            ssa[fr] += v0.x*v0.x + v0.y*v0.y + v0.z*v0.z + v0.w*v0.w
                     + v1.x*v1.x + v1.y*v1.y + v1.z*v1.z + v1.w*v1.w;
            s16x8 a;
            a[0] = f2bf(v0.x); a[1] = f2bf(v0.y); a[2] = f2bf(v0.z); a[3] = f2bf(v0.w);
            a[4] = f2bf(v1.x); a[5] = f2bf(v1.y); a[6] = f2bf(v1.z); a[7] = f2bf(v1.w);
            af[fr] = a;
        }
        #pragma unroll
        for (int fc = 0; fc < 4; ++fc) {
            const float* g = Bb + (size_t)(fc * 16 + l15) * DD + kof;
            f32x4 v0 = *reinterpret_cast<const f32x4*>(g);
            f32x4 v1 = *reinterpret_cast<const f32x4*>(g + 4);
            ssb[fc] += v0.x*v0.x + v0.y*v0.y + v0.z*v0.z + v0.w*v0.w
                     + v1.x*v1.x + v1.y*v1.y + v1.z*v1.z + v1.w*v1.w;
            s16x8 o;
            o[0] = f2bf(v0.x); o[1] = f2bf(v0.y); o[2] = f2bf(v0.z); o[3] = f2bf(v0.w);
            o[4] = f2bf(v1.x); o[5] = f2bf(v1.y); o[6] = f2bf(v1.z); o[7] = f2bf(v1.w);
            bf[fc] = o;
        }
        __builtin_amdgcn_s_setprio(1);
        #pragma unroll
        for (int fr = 0; fr < 4; ++fr)
            #pragma unroll
            for (int fc = 0; fc < 4; ++fc)
                acc[fr][fc] = __builtin_amdgcn_mfma_f32_16x16x32_bf16(
                    af[fr], bf[fc], acc[fr][fc], 0, 0, 0);
        __builtin_amdgcn_s_setprio(0);
    }

    // ---- inv norms, wave-private ----
    // reduce partial SS over the 4 lhi groups (lanes sharing l15)
    #pragma unroll
    for (int i = 0; i < 4; ++i) {
        ssa[i] += __shfl_xor(ssa[i], 16, 64);
        ssa[i] += __shfl_xor(ssa[i], 32, 64);
        ssb[i] += __shfl_xor(ssb[i], 16, 64);
        ssb[i] += __shfl_xor(ssb[i], 32, 64);
    }
    // acc element (fr, fc, r) is sim[row = fr*16 + lhi*4 + r][col = fc*16 + l15].
    // row-SS lives at lane l15 == row: transpose via width-16 shuffle.
    float ia[4][4], ib4[4];
    #pragma unroll
    for (int fr = 0; fr < 4; ++fr)
        #pragma unroll
        for (int r = 0; r < 4; ++r)
            ia[fr][r] = 1.0f / fmaxf(sqrtf(__shfl(ssa[fr], lhi * 4 + r, 16)), 1e-8f);
    #pragma unroll
    for (int fc = 0; fc < 4; ++fc)
        ib4[fc] = 1.0f / fmaxf(sqrtf(ssb[fc]), 1e-8f);

    #pragma unroll
    for (int fr = 0; fr < 4; ++fr)
        #pragma unroll
        for (int fc = 0; fc < 4; ++fc)
            #pragma unroll
            for (int r = 0; r < 4; ++r)
                acc[fr][fc][r] *= ia[fr][r] * ib4[fc];

    // ---- epilogue: masked row/col maxes ----
    int m2[4];
    #pragma unroll
    for (int fc = 0; fc < 4; ++fc)
        m2[fc] = mask2[b * LL + tc * 128 + wc * 64 + fc * 16 + l15];
    int m1[4][4];
    #pragma unroll
    for (int fr = 0; fr < 4; ++fr)
        #pragma unroll
        for (int r = 0; r < 4; ++r)
            m1[fr][r] = mask1[b * LL + tr * 128 + wr * 64 + fr * 16 + lhi * 4 + r];

    // row max: per (fr,r) max over this wave's 64 cols (mask2-gated)
    #pragma unroll
    for (int fr = 0; fr < 4; ++fr) {
        #pragma unroll
        for (int r = 0; r < 4; ++r) {
            float v = -INFINITY;
            #pragma unroll
            for (int fc = 0; fc < 4; ++fc)
                if (m2[fc]) v = fmaxf(v, acc[fr][fc][r]);
            v = fmaxf(v, __shfl_xor(v, 1, 64));
            v = fmaxf(v, __shfl_xor(v, 2, 64));
            v = fmaxf(v, __shfl_xor(v, 4, 64));
            v = fmaxf(v, __shfl_xor(v, 8, 64));
            if (l15 == 0)
                atomicMax(&rowmax_u[b * LL + tr * 128 + wr * 64 + fr * 16 + lhi * 4 + r],
                          fmap(v));
        }
    }
    // col max: per fc col, max over this wave's 64 rows (mask1-gated)
    #pragma unroll
    for (int fc = 0; fc < 4; ++fc) {
        float v = -INFINITY;
        #pragma unroll
        for (int fr = 0; fr < 4; ++fr)
            #pragma unroll
            for (int r = 0; r < 4; ++r)
                if (m1[fr][r]) v = fmaxf(v, acc[fr][fc][r]);
        v = fmaxf(v, __shfl_xor(v, 16, 64));
        v = fmaxf(v, __shfl_xor(v, 32, 64));
        if (lhi == 0)
            atomicMax(&colmax_u[b * LL + tc * 128 + wc * 64 + fc * 16 + l15], fmap(v));
    }
}

__global__ __launch_bounds__(64) void finalize_kernel(
        const unsigned* __restrict__ rowmax_u, const unsigned* __restrict__ colmax_u,
        const int* __restrict__ mask1, const int* __restrict__ mask2,
        float* __restrict__ out) {
    int b = blockIdx.x;
    int lane = threadIdx.x;
    float s1 = 0.f, c1 = 0.f, s2 = 0.f, c2 = 0.f;
    for (int i = lane; i < LL; i += 64) {
        if (mask1[b * LL + i]) { s1 += funmap(rowmax_u[b * LL + i]); c1 += 1.f; }
        if (mask2[b * LL + i]) { s2 += funmap(colmax_u[b * LL + i]); c2 += 1.f; }
    }
    #pragma unroll
    for (int off = 32; off >= 1; off >>= 1) {
        s1 += __shfl_xor(s1, off, 64);
        c1 += __shfl_xor(c1, off, 64);
        s2 += __shfl_xor(s2, off, 64);
        c2 += __shfl_xor(c2, off, 64);
    }
    if (lane == 0) out[b] = 0.5f * (s1 / c1 + s2 / c2);
}

extern "C" void kernel_launch(void* const* d_in, const int* in_sizes, int n_in,
                              void* d_out, int out_size, void* d_ws, size_t ws_size,
                              hipStream_t stream) {
    const float* x1    = (const float*)d_in[0];
    const int*   mask1 = (const int*)d_in[1];
    const float* x2    = (const float*)d_in[2];
    const int*   mask2 = (const int*)d_in[3];
    float* out = (float*)d_out;

    unsigned* rowmax_u = (unsigned*)d_ws;
    unsigned* colmax_u = rowmax_u + NB * LL;

    init_kernel<<<(2 * NB * LL + 255) / 256, 256, 0, stream>>>(rowmax_u, 2 * NB * LL);
    simdirect<<<NB * 16, 256, 0, stream>>>(x1, x2, mask1, mask2,
                                           rowmax_u, colmax_u);
    finalize_kernel<<<NB, 64, 0, stream>>>(rowmax_u, colmax_u, mask1, mask2, out);
}

// Round 10
// 249.140 us; speedup vs baseline: 1.1345x; 1.1345x over previous
//
#include <hip/hip_runtime.h>
#include <hip/hip_bf16.h>

#define NB 128
#define LL 512
#define DD 512

typedef __attribute__((ext_vector_type(4))) float  f32x4;
typedef __attribute__((ext_vector_type(8))) short  s16x8;

__device__ __forceinline__ short f2bf(float f) {
    __hip_bfloat16 h = __float2bfloat16(f);
    return *reinterpret_cast<short*>(&h);
}

// monotone float<->uint mapping so atomicMax(uint) == float max
__device__ __forceinline__ unsigned fmap(float f) {
    unsigned u = __float_as_uint(f);
    return (u & 0x80000000u) ? ~u : (u | 0x80000000u);
}
__device__ __forceinline__ float funmap(unsigned u) {
    unsigned b = (u & 0x80000000u) ? (u ^ 0x80000000u) : ~u;
    return __uint_as_float(b);
}

__global__ __launch_bounds__(256) void init_kernel(unsigned* __restrict__ p, int n) {
    int i = blockIdx.x * 256 + threadIdx.x;
    if (i < n) p[i] = 0u;  // 0 < fmap of any real value
}

// Fused: 128x128x512 GEMM + on-the-fly sum-of-squares + inv-norm scaling +
// masked row/col max.
// LDS holds bf16 (converted ONCE, on stage-write). Single 32KB K-tile buffer
// (BK=64), split barrier. T14 split staging: ISSUE (global->persistent regs)
// before the compute phase so HBM latency hides under ds_read+MFMA; COMMIT
// (SS + cvt + conflict-free swizzled ds_write_b128) after the barrier.
// (256,3): 168-reg cap fits acc(64)+stage(64)+transients without spill,
// 3 blocks/CU (R4/R8 lesson: (256,4)'s 128-reg cap spills).
__global__ __launch_bounds__(256, 3) void simgemm_fused(
        const float* __restrict__ x1, const float* __restrict__ x2,
        const int* __restrict__ mask1, const int* __restrict__ mask2,
        unsigned* __restrict__ rowmax_u, unsigned* __restrict__ colmax_u) {
    __shared__ __align__(16) char lds[33792];
    // A @0 (16KB bf16), B @16384 (16KB bf16), invA @32768, invB @33280
    char* As0 = lds;
    char* Bs0 = lds + 16384;
    float* invA_lds = reinterpret_cast<float*>(lds + 32768);
    float* invB_lds = reinterpret_cast<float*>(lds + 33280);

    int bid = blockIdx.x;
    int lid = (bid & 7) * 256 + (bid >> 3);   // XCD-chunked bijective swizzle (nwg=2048)
    int b   = lid >> 4;
    int tr  = (lid >> 2) & 3;
    int tc  = lid & 3;

    int tid  = threadIdx.x;
    int lane = tid & 63;
    int w    = tid >> 6;
    int wr = w >> 1, wc = w & 1;
    int l15 = lane & 15, lhi = lane >> 4;
    int rg3 = lane >> 3, sl = lane & 7;       // staging: 8 rows x 8 k-slots per wave pass

    const float* Ab = x1 + ((size_t)b * LL + tr * 128) * DD;
    const float* Bb = x2 + ((size_t)b * LL + tc * 128) * DD;

    float ssa[4] = {0.f, 0.f, 0.f, 0.f};
    float ssb[4] = {0.f, 0.f, 0.f, 0.f};

    // persistent in-flight staging registers (live across the compute phase)
    f32x4 va[4][2], vb[4][2];

    f32x4 acc[4][4];
    #pragma unroll
    for (int fr = 0; fr < 4; ++fr)
        #pragma unroll
        for (int fc = 0; fc < 4; ++fc) {
            acc[fr][fc].x = 0.f; acc[fr][fc].y = 0.f;
            acc[fr][fc].z = 0.f; acc[fr][fc].w = 0.f;
        }

    // thread (w, rg3, sl) owns rows w*32 + i*8 + rg3 (i=0..3), fp32 cols
    // sl*8..sl*8+7 of the K-tile: 8+8 dwordx4 loads per t-step.
    #define ISSUE(t)                                                              \
        {                                                                         \
            _Pragma("unroll")                                                     \
            for (int i = 0; i < 4; ++i) {                                         \
                int row = w * 32 + i * 8 + rg3;                                   \
                const float* ga = Ab + (size_t)row * DD + (t) * 64 + sl * 8;      \
                va[i][0] = *reinterpret_cast<const f32x4*>(ga);                   \
                va[i][1] = *reinterpret_cast<const f32x4*>(ga + 4);               \
                const float* gb = Bb + (size_t)row * DD + (t) * 64 + sl * 8;      \
                vb[i][0] = *reinterpret_cast<const f32x4*>(gb);                   \
                vb[i][1] = *reinterpret_cast<const f32x4*>(gb + 4);               \
            }                                                                     \
        }

    #define COMMIT()                                                              \
        {                                                                         \
            _Pragma("unroll")                                                     \
            for (int i = 0; i < 4; ++i) {                                         \
                int row = w * 32 + i * 8 + rg3;                                   \
                unsigned byte = (unsigned)(row * 128 + sl * 16)                   \
                              ^ ((unsigned)(row & 7) << 4);                       \
                f32x4 v0 = va[i][0], v1 = va[i][1];                               \
                ssa[i] += v0.x*v0.x + v0.y*v0.y + v0.z*v0.z + v0.w*v0.w           \
                        + v1.x*v1.x + v1.y*v1.y + v1.z*v1.z + v1.w*v1.w;          \
                s16x8 oa;                                                         \
                oa[0] = f2bf(v0.x); oa[1] = f2bf(v0.y);                           \
                oa[2] = f2bf(v0.z); oa[3] = f2bf(v0.w);                           \
                oa[4] = f2bf(v1.x); oa[5] = f2bf(v1.y);                           \
                oa[6] = f2bf(v1.z); oa[7] = f2bf(v1.w);                           \
                *reinterpret_cast<s16x8*>(As0 + byte) = oa;                       \
                f32x4 u0 = vb[i][0], u1 = vb[i][1];                               \
                ssb[i] += u0.x*u0.x + u0.y*u0.y + u0.z*u0.z + u0.w*u0.w           \
                        + u1.x*u1.x + u1.y*u1.y + u1.z*u1.z + u1.w*u1.w;          \
                s16x8 ob;                                                         \
                ob[0] = f2bf(u0.x); ob[1] = f2bf(u0.y);                           \
                ob[2] = f2bf(u0.z); ob[3] = f2bf(u0.w);                           \
                ob[4] = f2bf(u1.x); ob[5] = f2bf(u1.y);                           \
                ob[6] = f2bf(u1.z); ob[7] = f2bf(u1.w);                           \
                *reinterpret_cast<s16x8*>(Bs0 + byte) = ob;                       \
            }                                                                     \
        }

    // prologue: K-tile 0
    ISSUE(0);
    COMMIT();
    __syncthreads();

    for (int t = 0; t < 8; ++t) {
        if (t < 7) ISSUE(t + 1);           // loads fly under ds_read + MFMA
        // compute on the staged tile: 16 ds_read_b128 + 32 MFMA per wave
        #pragma unroll
        for (int ks = 0; ks < 2; ++ks) {
            s16x8 af[4], bf[4];
            #pragma unroll
            for (int fr = 0; fr < 4; ++fr) {
                int row = wr * 64 + fr * 16 + l15;
                unsigned byte = (unsigned)(row * 128 + ks * 64 + lhi * 16)
                              ^ ((unsigned)(row & 7) << 4);
                af[fr] = *reinterpret_cast<const s16x8*>(As0 + byte);
            }
            #pragma unroll
            for (int fc = 0; fc < 4; ++fc) {
                int crow = wc * 64 + fc * 16 + l15;
                unsigned byte = (unsigned)(crow * 128 + ks * 64 + lhi * 16)
                              ^ ((unsigned)(crow & 7) << 4);
                bf[fc] = *reinterpret_cast<const s16x8*>(Bs0 + byte);
            }
            __builtin_amdgcn_s_setprio(1);
            #pragma unroll
            for (int fr = 0; fr < 4; ++fr)
                #pragma unroll
                for (int fc = 0; fc < 4; ++fc)
                    acc[fr][fc] = __builtin_amdgcn_mfma_f32_16x16x32_bf16(
                        af[fr], bf[fc], acc[fr][fc], 0, 0, 0);
            __builtin_amdgcn_s_setprio(0);
        }
        __syncthreads();                   // all reads of tile t done
        if (t < 7) {
            COMMIT();                      // cvt + SS + write tile t+1
            __syncthreads();               // writes visible block-wide
        }
    }

    // ---- inv norms: each row's SS is spread across its 8 slot-lanes ----
    #pragma unroll
    for (int i = 0; i < 4; ++i) {
        ssa[i] += __shfl_xor(ssa[i], 1, 64);
        ssa[i] += __shfl_xor(ssa[i], 2, 64);
        ssa[i] += __shfl_xor(ssa[i], 4, 64);
        ssb[i] += __shfl_xor(ssb[i], 1, 64);
        ssb[i] += __shfl_xor(ssb[i], 2, 64);
        ssb[i] += __shfl_xor(ssb[i], 4, 64);
    }
    if (sl == 0) {
        #pragma unroll
        for (int i = 0; i < 4; ++i) {
            int row = w * 32 + i * 8 + rg3;
            invA_lds[row] = 1.0f / fmaxf(sqrtf(ssa[i]), 1e-8f);
            invB_lds[row] = 1.0f / fmaxf(sqrtf(ssb[i]), 1e-8f);
        }
    }
    __syncthreads();

    // ---- scale by inv norms ----
    float ia[4][4], ib4[4];
    #pragma unroll
    for (int fr = 0; fr < 4; ++fr)
        #pragma unroll
        for (int r = 0; r < 4; ++r)
            ia[fr][r] = invA_lds[wr * 64 + fr * 16 + lhi * 4 + r];
    #pragma unroll
    for (int fc = 0; fc < 4; ++fc)
        ib4[fc] = invB_lds[wc * 64 + fc * 16 + l15];
    #pragma unroll
    for (int fr = 0; fr < 4; ++fr)
        #pragma unroll
        for (int fc = 0; fc < 4; ++fc)
            #pragma unroll
            for (int r = 0; r < 4; ++r)
                acc[fr][fc][r] *= ia[fr][r] * ib4[fc];

    // ---- epilogue: masked row/col maxes ----
    int m2[4];
    #pragma unroll
    for (int fc = 0; fc < 4; ++fc)
        m2[fc] = mask2[b * LL + tc * 128 + wc * 64 + fc * 16 + l15];
    int m1[4][4];
    #pragma unroll
    for (int fr = 0; fr < 4; ++fr)
        #pragma unroll
        for (int r = 0; r < 4; ++r)
            m1[fr][r] = mask1[b * LL + tr * 128 + wr * 64 + fr * 16 + lhi * 4 + r];

    // row max: per (fr,r) max over this wave's 64 cols (mask2-gated)
    #pragma unroll
    for (int fr = 0; fr < 4; ++fr) {
        #pragma unroll
        for (int r = 0; r < 4; ++r) {
            float v = -INFINITY;
            #pragma unroll
            for (int fc = 0; fc < 4; ++fc)
                if (m2[fc]) v = fmaxf(v, acc[fr][fc][r]);
            v = fmaxf(v, __shfl_xor(v, 1, 64));
            v = fmaxf(v, __shfl_xor(v, 2, 64));
            v = fmaxf(v, __shfl_xor(v, 4, 64));
            v = fmaxf(v, __shfl_xor(v, 8, 64));
            if (l15 == 0)
                atomicMax(&rowmax_u[b * LL + tr * 128 + wr * 64 + fr * 16 + lhi * 4 + r],
                          fmap(v));
        }
    }
    // col max: per fc col, max over this wave's 64 rows (mask1-gated)
    #pragma unroll
    for (int fc = 0; fc < 4; ++fc) {
        float v = -INFINITY;
        #pragma unroll
        for (int fr = 0; fr < 4; ++fr)
            #pragma unroll
            for (int r = 0; r < 4; ++r)
                if (m1[fr][r]) v = fmaxf(v, acc[fr][fc][r]);
        v = fmaxf(v, __shfl_xor(v, 16, 64));
        v = fmaxf(v, __shfl_xor(v, 32, 64));
        if (lhi == 0)
            atomicMax(&colmax_u[b * LL + tc * 128 + wc * 64 + fc * 16 + l15], fmap(v));
    }
    #undef ISSUE
    #undef COMMIT
}

__global__ __launch_bounds__(64) void finalize_kernel(
        const unsigned* __restrict__ rowmax_u, const unsigned* __restrict__ colmax_u,
        const int* __restrict__ mask1, const int* __restrict__ mask2,
        float* __restrict__ out) {
    int b = blockIdx.x;
    int lane = threadIdx.x;
    float s1 = 0.f, c1 = 0.f, s2 = 0.f, c2 = 0.f;
    for (int i = lane; i < LL; i += 64) {
        if (mask1[b * LL + i]) { s1 += funmap(rowmax_u[b * LL + i]); c1 += 1.f; }
        if (mask2[b * LL + i]) { s2 += funmap(colmax_u[b * LL + i]); c2 += 1.f; }
    }
    #pragma unroll
    for (int off = 32; off >= 1; off >>= 1) {
        s1 += __shfl_xor(s1, off, 64);
        c1 += __shfl_xor(c1, off, 64);
        s2 += __shfl_xor(s2, off, 64);
        c2 += __shfl_xor(c2, off, 64);
    }
    if (lane == 0) out[b] = 0.5f * (s1 / c1 + s2 / c2);
}

extern "C" void kernel_launch(void* const* d_in, const int* in_sizes, int n_in,
                              void* d_out, int out_size, void* d_ws, size_t ws_size,
                              hipStream_t stream) {
    const float* x1    = (const float*)d_in[0];
    const int*   mask1 = (const int*)d_in[1];
    const float* x2    = (const float*)d_in[2];
    const int*   mask2 = (const int*)d_in[3];
    float* out = (float*)d_out;

    unsigned* rowmax_u = (unsigned*)d_ws;
    unsigned* colmax_u = rowmax_u + NB * LL;

    init_kernel<<<(2 * NB * LL + 255) / 256, 256, 0, stream>>>(rowmax_u, 2 * NB * LL);
    simgemm_fused<<<NB * 16, 256, 0, stream>>>(x1, x2, mask1, mask2,
                                               rowmax_u, colmax_u);
    finalize_kernel<<<NB, 64, 0, stream>>>(rowmax_u, colmax_u, mask1, mask2, out);
}

// Round 11
// 143.721 us; speedup vs baseline: 1.9667x; 1.7335x over previous
//
#include <hip/hip_runtime.h>
#include <hip/hip_bf16.h>

#define NB 128
#define LL 512
#define DD 512

typedef __attribute__((ext_vector_type(4))) float  f32x4;
typedef __attribute__((ext_vector_type(8))) short  s16x8;

#define AS1 __attribute__((address_space(1)))
#define AS3 __attribute__((address_space(3)))

__device__ __forceinline__ short f2bf(float f) {
    __hip_bfloat16 h = __float2bfloat16(f);
    return *reinterpret_cast<short*>(&h);
}

// monotone float<->uint mapping so atomicMax(uint) == float max
__device__ __forceinline__ unsigned fmap(float f) {
    unsigned u = __float_as_uint(f);
    return (u & 0x80000000u) ? ~u : (u | 0x80000000u);
}
__device__ __forceinline__ float funmap(unsigned u) {
    unsigned b = (u & 0x80000000u) ? (u ^ 0x80000000u) : ~u;
    return __uint_as_float(b);
}

__device__ __forceinline__ void gl16(const void* g, void* l) {
    __builtin_amdgcn_global_load_lds((const AS1 unsigned int*)g,
                                     (AS3 unsigned int*)l, 16, 0, 0);
}

// Pass 1: normalize fp32 rows -> bf16, 4 rows per wave (128 B/lane in
// flight), grid-stride; also zeroes the max buffers (folds init_kernel).
__global__ __launch_bounds__(256) void normalize_fast(
        const float* __restrict__ x1, const float* __restrict__ x2,
        short* __restrict__ n1, short* __restrict__ n2,
        unsigned* __restrict__ maxbuf) {
    int tid = threadIdx.x;
    int gid = blockIdx.x * 256 + tid;
    if (gid < 2 * NB * LL) maxbuf[gid] = 0u;   // 0 < fmap of any real value

    int gw   = blockIdx.x * 4 + (tid >> 6);    // global wave id (8192 waves)
    int lane = tid & 63;

    for (int r0 = gw * 4; r0 < 2 * NB * LL; r0 += 8192 * 4) {
        f32x4 v[4][2];
        #pragma unroll
        for (int i = 0; i < 4; ++i) {
            int row = r0 + i;
            const float* x = (row < NB * LL)
                ? x1 + (size_t)row * DD
                : x2 + (size_t)(row - NB * LL) * DD;
            const f32x4* p = reinterpret_cast<const f32x4*>(x);
            v[i][0] = p[2 * lane];
            v[i][1] = p[2 * lane + 1];
        }
        #pragma unroll
        for (int i = 0; i < 4; ++i) {
            f32x4 a = v[i][0], c = v[i][1];
            float ss = a.x*a.x + a.y*a.y + a.z*a.z + a.w*a.w
                     + c.x*c.x + c.y*c.y + c.z*c.z + c.w*c.w;
            #pragma unroll
            for (int off = 32; off >= 1; off >>= 1)
                ss += __shfl_xor(ss, off, 64);
            float s = 1.0f / fmaxf(sqrtf(ss), 1e-8f);
            s16x8 o;
            o[0] = f2bf(a.x * s); o[1] = f2bf(a.y * s);
            o[2] = f2bf(a.z * s); o[3] = f2bf(a.w * s);
            o[4] = f2bf(c.x * s); o[5] = f2bf(c.y * s);
            o[6] = f2bf(c.z * s); o[7] = f2bf(c.w * s);
            int row = r0 + i;
            short* n = (row < NB * LL)
                ? n1 + (size_t)row * DD
                : n2 + (size_t)(row - NB * LL) * DD;
            reinterpret_cast<s16x8*>(n)[lane] = o;
        }
    }
}

// stage 128 rows x 64 k (bf16) into a 16 KB LDS buffer, linear dest +
// inverse-swizzled global source: logical byte = linear ^ ((row&7)<<4)
__device__ __forceinline__ void stage128x64(
        const short* __restrict__ src, int k0, char* ldsb, int w, int lane) {
    #pragma unroll
    for (int j = 0; j < 4; ++j) {
        int L   = (j * 4 + w) * 1024 + lane * 16;   // linear LDS byte offset
        int row = L >> 7;                           // 128 B per row
        int kg  = ((L >> 4) & 7) ^ (row & 7);       // inverse swizzle on source
        const short* g = src + (size_t)row * DD + k0 + kg * 8;
        gl16(g, ldsb + (j * 4 + w) * 1024);         // HW adds lane*16
    }
}

// Pass 2: 128x128x512 bf16 GEMM + masked row/col max (R2-proven kernel).
__global__ __launch_bounds__(256) void simgemm_kernel(
        const short* __restrict__ n1, const short* __restrict__ n2,
        const int* __restrict__ mask1, const int* __restrict__ mask2,
        unsigned* __restrict__ rowmax_u, unsigned* __restrict__ colmax_u) {
    __shared__ __align__(16) char lds[65536];
    // layout: A0 @0, B0 @16384, A1 @32768, B1 @49152

    int bid = blockIdx.x;
    int lid = (bid & 7) * 256 + (bid >> 3);   // XCD-chunked bijective swizzle (nwg=2048)
    int b   = lid >> 4;
    int tr  = (lid >> 2) & 3;
    int tc  = lid & 3;

    int tid  = threadIdx.x;
    int lane = tid & 63;
    int w    = tid >> 6;
    int wr = w >> 1, wc = w & 1;
    int l15 = lane & 15, lhi = lane >> 4;

    const short* Abase = n1 + ((size_t)b * LL + tr * 128) * DD;
    const short* Bbase = n2 + ((size_t)b * LL + tc * 128) * DD;

    f32x4 acc[4][4];
    #pragma unroll
    for (int fr = 0; fr < 4; ++fr)
        #pragma unroll
        for (int fc = 0; fc < 4; ++fc) {
            acc[fr][fc].x = 0.f; acc[fr][fc].y = 0.f;
            acc[fr][fc].z = 0.f; acc[fr][fc].w = 0.f;
        }

    // prologue: stage K-tile 0 into buffer 0
    stage128x64(Abase, 0, lds,         w, lane);
    stage128x64(Bbase, 0, lds + 16384, w, lane);
    __syncthreads();

    int cur = 0;
    for (int t = 0; t < 8; ++t) {
        // issue next-tile loads first so they fly under ds_read+MFMA
        if (t < 7) {
            char* nb = lds + (cur ^ 1) * 32768;
            stage128x64(Abase, (t + 1) * 64, nb,         w, lane);
            stage128x64(Bbase, (t + 1) * 64, nb + 16384, w, lane);
        }
        char* As = lds + cur * 32768;
        char* Bs = As + 16384;
        #pragma unroll
        for (int ks = 0; ks < 2; ++ks) {
            s16x8 af[4], bf[4];
            #pragma unroll
            for (int fr = 0; fr < 4; ++fr) {
                int row = wr * 64 + fr * 16 + l15;
                unsigned byte = (unsigned)(row * 128 + ks * 64 + lhi * 16)
                              ^ ((unsigned)(row & 7) << 4);
                af[fr] = *reinterpret_cast<const s16x8*>(As + byte);
            }
            #pragma unroll
            for (int fc = 0; fc < 4; ++fc) {
                int crow = wc * 64 + fc * 16 + l15;
                unsigned byte = (unsigned)(crow * 128 + ks * 64 + lhi * 16)
                              ^ ((unsigned)(crow & 7) << 4);
                bf[fc] = *reinterpret_cast<const s16x8*>(Bs + byte);
            }
            #pragma unroll
            for (int fr = 0; fr < 4; ++fr)
                #pragma unroll
                for (int fc = 0; fc < 4; ++fc)
                    acc[fr][fc] = __builtin_amdgcn_mfma_f32_16x16x32_bf16(
                        af[fr], bf[fc], acc[fr][fc], 0, 0, 0);
        }
        __syncthreads();   // drains vmcnt (stage done) + all reads of cur done
        cur ^= 1;
    }

    // ---- epilogue: masked row/col maxes ----
    int m2[4];
    #pragma unroll
    for (int fc = 0; fc < 4; ++fc)
        m2[fc] = mask2[b * LL + tc * 128 + wc * 64 + fc * 16 + l15];
    int m1[4][4];
    #pragma unroll
    for (int fr = 0; fr < 4; ++fr)
        #pragma unroll
        for (int r = 0; r < 4; ++r)
            m1[fr][r] = mask1[b * LL + tr * 128 + wr * 64 + fr * 16 + lhi * 4 + r];

    // row max: per (fr,r) max over this wave's 64 cols (mask2-gated)
    #pragma unroll
    for (int fr = 0; fr < 4; ++fr) {
        #pragma unroll
        for (int r = 0; r < 4; ++r) {
            float v = -INFINITY;
            #pragma unroll
            for (int fc = 0; fc < 4; ++fc)
                if (m2[fc]) v = fmaxf(v, acc[fr][fc][r]);
            v = fmaxf(v, __shfl_xor(v, 1, 64));
            v = fmaxf(v, __shfl_xor(v, 2, 64));
            v = fmaxf(v, __shfl_xor(v, 4, 64));
            v = fmaxf(v, __shfl_xor(v, 8, 64));
            if (l15 == 0)
                atomicMax(&rowmax_u[b * LL + tr * 128 + wr * 64 + fr * 16 + lhi * 4 + r],
                          fmap(v));
        }
    }
    // col max: per fc col, max over this wave's 64 rows (mask1-gated)
    #pragma unroll
    for (int fc = 0; fc < 4; ++fc) {
        float v = -INFINITY;
        #pragma unroll
        for (int fr = 0; fr < 4; ++fr)
            #pragma unroll
            for (int r = 0; r < 4; ++r)
                if (m1[fr][r]) v = fmaxf(v, acc[fr][fc][r]);
        v = fmaxf(v, __shfl_xor(v, 16, 64));
        v = fmaxf(v, __shfl_xor(v, 32, 64));
        if (lhi == 0)
            atomicMax(&colmax_u[b * LL + tc * 128 + wc * 64 + fc * 16 + l15], fmap(v));
    }
}

__global__ __launch_bounds__(64) void finalize_kernel(
        const unsigned* __restrict__ rowmax_u, const unsigned* __restrict__ colmax_u,
        const int* __restrict__ mask1, const int* __restrict__ mask2,
        float* __restrict__ out) {
    int b = blockIdx.x;
    int lane = threadIdx.x;
    float s1 = 0.f, c1 = 0.f, s2 = 0.f, c2 = 0.f;
    for (int i = lane; i < LL; i += 64) {
        if (mask1[b * LL + i]) { s1 += funmap(rowmax_u[b * LL + i]); c1 += 1.f; }
        if (mask2[b * LL + i]) { s2 += funmap(colmax_u[b * LL + i]); c2 += 1.f; }
    }
    #pragma unroll
    for (int off = 32; off >= 1; off >>= 1) {
        s1 += __shfl_xor(s1, off, 64);
        c1 += __shfl_xor(c1, off, 64);
        s2 += __shfl_xor(s2, off, 64);
        c2 += __shfl_xor(c2, off, 64);
    }
    if (lane == 0) out[b] = 0.5f * (s1 / c1 + s2 / c2);
}

extern "C" void kernel_launch(void* const* d_in, const int* in_sizes, int n_in,
                              void* d_out, int out_size, void* d_ws, size_t ws_size,
                              hipStream_t stream) {
    const float* x1    = (const float*)d_in[0];
    const int*   mask1 = (const int*)d_in[1];
    const float* x2    = (const float*)d_in[2];
    const int*   mask2 = (const int*)d_in[3];
    float* out = (float*)d_out;

    size_t nElem = (size_t)NB * LL * DD;   // 33.5 M
    short* n1 = (short*)d_ws;
    short* n2 = n1 + nElem;
    unsigned* rowmax_u = (unsigned*)(n2 + nElem);
    unsigned* colmax_u = rowmax_u + NB * LL;

    normalize_fast<<<2048, 256, 0, stream>>>(x1, x2, n1, n2, rowmax_u);
    simgemm_kernel<<<NB * 16, 256, 0, stream>>>(n1, n2, mask1, mask2,
                                                rowmax_u, colmax_u);
    finalize_kernel<<<NB, 64, 0, stream>>>(rowmax_u, colmax_u, mask1, mask2, out);
}